// Round 5
// baseline (339.350 us; speedup 1.0000x reference)
//
#include <hip/hip_runtime.h>

#define N 8192
#define D 128
#define MARGIN 0.5f
#define FLT_BIG 3.402823466e+38f
#define NBLK 2048  // k_mine grid (64 x 32)

typedef __bf16 bf16x8 __attribute__((ext_vector_type(8)));
typedef float f32x4 __attribute__((ext_vector_type(4)));
typedef unsigned short u16x8 __attribute__((ext_vector_type(8)));

__device__ __forceinline__ unsigned short f2bf_rne(float f) {
  unsigned u = __float_as_uint(f);
  u += 0x7FFFu + ((u >> 16) & 1u);  // round-to-nearest-even (inputs finite)
  return (unsigned short)(u >> 16);
}

// xb layout: MFMA-fragment-major. frag[tile][k][lane][8] ushorts, where
// tile = row>>4, lane = quad*16 + (row&15), chunk (4k+quad) = row bytes
// [k*64 + quad*16 .. +16). A and B fragments of the Gram matmul share this
// exact formula, so every fragment load is base + lane*16B (fully coalesced).
#define FRAG_OFF(tile, k, lane) ((size_t)(tile) * 2048 + (size_t)(k) * 512 + (size_t)(lane) * 8)

// ---------------- K1: fp32->bf16 fragment-swizzle + row norms + init ----------
// grid 512 x 256: thread = (row, chunk c): 16 rows/block, 16 chunks/row.
__global__ void k_prep(const float* __restrict__ x, const int* __restrict__ lab,
                       unsigned short* __restrict__ xb, float* __restrict__ sq,
                       unsigned* __restrict__ posw, unsigned* __restrict__ negw,
                       unsigned* __restrict__ hist, unsigned* __restrict__ ticket) {
  const int t = threadIdx.x;
  const int row = blockIdx.x * 16 + (t >> 4);
  const int c = t & 15;
  const float4 v0 = ((const float4*)x)[row * 32 + c * 2];
  const float4 v1 = ((const float4*)x)[row * 32 + c * 2 + 1];
  u16x8 o;
  o[0] = f2bf_rne(v0.x); o[1] = f2bf_rne(v0.y);
  o[2] = f2bf_rne(v0.z); o[3] = f2bf_rne(v0.w);
  o[4] = f2bf_rne(v1.x); o[5] = f2bf_rne(v1.y);
  o[6] = f2bf_rne(v1.z); o[7] = f2bf_rne(v1.w);
  // chunk c -> k = c>>2, quad = c&3; lane = quad*16 + (row&15)
  *(u16x8*)(xb + FRAG_OFF(row >> 4, c >> 2, ((c & 3) * 16) + (row & 15))) = o;
  float s = v0.x * v0.x + v0.y * v0.y + v0.z * v0.z + v0.w * v0.w +
            v1.x * v1.x + v1.y * v1.y + v1.z * v1.z + v1.w * v1.w;
#pragma unroll
  for (int off = 1; off < 16; off <<= 1) s += __shfl_xor(s, off, 64);
  if (c == 0) {
    sq[row] = s;
    posw[row] = 0u;           // max(d2) accumulator
    negw[row] = 0x7F800000u;  // min(d2) accumulator = +inf
  }

  if (blockIdx.x == 0) {  // label histogram
    __shared__ unsigned h[8];
    if (t < 8) h[t] = 0u;
    __syncthreads();
    unsigned long long cA = 0ull, cB = 0ull;  // 4x16-bit packed counters each
#pragma unroll
    for (int it = 0; it < 32; ++it) {
      const int l = lab[t + it * 256] & 7;
      if (l < 4) cA += 1ull << (l * 16);
      else       cB += 1ull << ((l - 4) * 16);
    }
#pragma unroll
    for (int off = 1; off < 64; off <<= 1) {
      cA += __shfl_xor(cA, off, 64);
      cB += __shfl_xor(cB, off, 64);
    }
    if ((t & 63) == 0) {
#pragma unroll
      for (int q = 0; q < 4; ++q) {
        atomicAdd(&h[q],     (unsigned)((cA >> (q * 16)) & 0xFFFFu));
        atomicAdd(&h[4 + q], (unsigned)((cB >> (q * 16)) & 0xFFFFu));
      }
    }
    __syncthreads();
    if (t < 8) hist[t] = h[t];
    if (t == 0) ticket[0] = 0u;
  }
}

// ---------------- K2: fused GEMM + mining + tail (no LDS, no loop barriers) --
// grid (64,32) x 256thr. Each wave: 32 i-rows x 256 j-rows, fully independent.
// Session lessons: R1 latency-bound (all pipes <20%); R2 waves/EU=8 spills
// (85 MB scratch); R3 depth-2 reg pipeline -3.5us only (issue distance ~320cy
// with TLP < ~500cy cold-L3 latency; the 256MB poison fill flushes L3 every
// iteration); R4 LDS staging catastrophic (barrier's vmcnt(0) drain serializes
// the DMA it was meant to hide -> 184us).
// This round: DEPTH-3 register pipeline (B bufs A/B/C, rotating; in-flight
// distance ~2 compute phases ~640cy > latency), VGPR ~122 < 128 cap at
// waves/EU=4 (no spill by design), plus tail fused via ticket (R4-validated).
// Self-term i==j contributes d2~bf16-noise to pos; true hardest positive is
// O(100) here and singleton classes are masked by hist validity -> no diag test.
__global__ __launch_bounds__(256, 4) void k_mine(
    const unsigned short* __restrict__ xb, const float* __restrict__ sq,
    const int* __restrict__ lab, unsigned* __restrict__ posw, unsigned* __restrict__ negw,
    const unsigned* __restrict__ hist, unsigned* __restrict__ ticket,
    float* __restrict__ out) {
  __shared__ float ls[4], cs[4];
  __shared__ unsigned lastf;

  const int t = threadIdx.x;
  const int w = t >> 6;
  const int lane = t & 63;
  const int col = lane & 15;   // MFMA m/n selector
  const int quad = lane >> 4;  // MFMA k-group / C row group
  const int i0 = blockIdx.x * 128 + w * 32;
  const int jbase = blockIdx.y * 256;

  // A fragments resident: 2 i-subtiles x 4 k-steps (coalesced loads)
  bf16x8 a[2][4];
#pragma unroll
  for (int is = 0; is < 2; ++is)
#pragma unroll
    for (int k = 0; k < 4; ++k)
      a[is][k] = *(const bf16x8*)(xb + FRAG_OFF((i0 >> 4) + is, k, lane));

  int labi[2][4];
#pragma unroll
  for (int is = 0; is < 2; ++is)
#pragma unroll
    for (int r = 0; r < 4; ++r) labi[is][r] = lab[i0 + is * 16 + quad * 4 + r];

  float pos[2][4], neg[2][4];
#pragma unroll
  for (int is = 0; is < 2; ++is)
#pragma unroll
    for (int r = 0; r < 4; ++r) { pos[is][r] = -FLT_BIG; neg[is][r] = FLT_BIG; }

  const float* sqp = sq + jbase + col;
  const int* labp = lab + jbase + col;
  const unsigned short* gb = xb + FRAG_OFF(jbase >> 4, 0, lane);

  bf16x8 b0A, b1A, b2A, b3A, b0B, b1B, b2B, b3B, b0C, b1C, b2C, b3C;
  float sqjA, sqjB, sqjC;
  int labjA, labjB, labjC;

#define LOADB(S, js_) do {                                        \
    const unsigned short* g = gb + (size_t)(js_) * 2048;          \
    b0##S = *(const bf16x8*)(g);                                  \
    b1##S = *(const bf16x8*)(g + 512);                            \
    b2##S = *(const bf16x8*)(g + 1024);                           \
    b3##S = *(const bf16x8*)(g + 1536);                           \
    sqj##S = sqp[(js_) * 16];                                     \
    labj##S = labp[(js_) * 16];                                   \
  } while (0)

#define COMPUTE(S) do {                                                        \
    f32x4 acc0 = {0.f, 0.f, 0.f, 0.f}, acc1 = {0.f, 0.f, 0.f, 0.f};           \
    acc0 = __builtin_amdgcn_mfma_f32_16x16x32_bf16(a[0][0], b0##S, acc0, 0, 0, 0); \
    acc1 = __builtin_amdgcn_mfma_f32_16x16x32_bf16(a[1][0], b0##S, acc1, 0, 0, 0); \
    acc0 = __builtin_amdgcn_mfma_f32_16x16x32_bf16(a[0][1], b1##S, acc0, 0, 0, 0); \
    acc1 = __builtin_amdgcn_mfma_f32_16x16x32_bf16(a[1][1], b1##S, acc1, 0, 0, 0); \
    acc0 = __builtin_amdgcn_mfma_f32_16x16x32_bf16(a[0][2], b2##S, acc0, 0, 0, 0); \
    acc1 = __builtin_amdgcn_mfma_f32_16x16x32_bf16(a[1][2], b2##S, acc1, 0, 0, 0); \
    acc0 = __builtin_amdgcn_mfma_f32_16x16x32_bf16(a[0][3], b3##S, acc0, 0, 0, 0); \
    acc1 = __builtin_amdgcn_mfma_f32_16x16x32_bf16(a[1][3], b3##S, acc1, 0, 0, 0); \
    _Pragma("unroll")                                                          \
    for (int r = 0; r < 4; ++r) {                                              \
      const float m0 = fmaf(-2.f, acc0[r], sqj##S);                            \
      const float m1 = fmaf(-2.f, acc1[r], sqj##S);                            \
      const bool s0 = (labi[0][r] == labj##S);                                 \
      const bool s1 = (labi[1][r] == labj##S);                                 \
      pos[0][r] = fmaxf(pos[0][r], s0 ? m0 : -FLT_BIG);                        \
      neg[0][r] = fminf(neg[0][r], s0 ? FLT_BIG : m0);                         \
      pos[1][r] = fmaxf(pos[1][r], s1 ? m1 : -FLT_BIG);                        \
      neg[1][r] = fminf(neg[1][r], s1 ? FLT_BIG : m1);                         \
    }                                                                          \
  } while (0)

  // depth-3 rotating pipeline: loads stay ~2 compute phases ahead.
  LOADB(A, 0);
  LOADB(B, 1);
#pragma unroll 1
  for (int js = 0; js < 12; js += 3) {
    LOADB(C, js + 2);
    COMPUTE(A);
    LOADB(A, js + 3);
    COMPUTE(B);
    LOADB(B, js + 4);
    COMPUTE(C);
  }
  // js = 12..15; A holds 12, B holds 13.
  LOADB(C, 14);
  COMPUTE(A);   // 12
  LOADB(A, 15);
  COMPUTE(B);   // 13
  COMPUTE(C);   // 14
  COMPUTE(A);   // 15

#undef LOADB
#undef COMPUTE

  // reduce the 16 cols sharing each i-row, add sq_i back, combine via atomics
#pragma unroll
  for (int is = 0; is < 2; ++is)
#pragma unroll
    for (int r = 0; r < 4; ++r) {
      float p = pos[is][r], n = neg[is][r];
#pragma unroll
      for (int off = 1; off < 16; off <<= 1) {
        p = fmaxf(p, __shfl_xor(p, off, 64));
        n = fminf(n, __shfl_xor(n, off, 64));
      }
      if (col == 0) {
        const int i = i0 + is * 16 + quad * 4 + r;
        const float sqi = sq[i];
        atomicMax(posw + i, __float_as_uint(fmaxf(sqi + p, 0.f)));
        atomicMin(negw + i, __float_as_uint(fmaxf(sqi + n, 0.f)));
      }
    }

  // ---- fused tail: last block (ticket) computes the final loss (R4-validated)
  __syncthreads();   // all this block's mining atomics issued & drained
  __threadfence();   // make them device-visible before the ticket
  if (t == 0) lastf = (atomicAdd(ticket, 1u) == (unsigned)(NBLK - 1)) ? 1u : 0u;
  __syncthreads();
  if (!lastf) return;

  float loss = 0.f, cnt = 0.f;
#pragma unroll 4
  for (int it = 0; it < 32; ++it) {
    const int i = t + it * 256;
    const float pd2 = __uint_as_float(
        __hip_atomic_load(posw + i, __ATOMIC_RELAXED, __HIP_MEMORY_SCOPE_AGENT));
    const float nd2 = __uint_as_float(
        __hip_atomic_load(negw + i, __ATOMIC_RELAXED, __HIP_MEMORY_SCOPE_AGENT));
    const unsigned c = hist[lab[i] & 7];
    if (c >= 2u && c < (unsigned)N) {
      loss += fmaxf(sqrtf(pd2) - sqrtf(fminf(nd2, FLT_BIG)) + MARGIN, 0.f);
      cnt += 1.f;
    }
  }
#pragma unroll
  for (int off = 1; off < 64; off <<= 1) {
    loss += __shfl_xor(loss, off, 64);
    cnt += __shfl_xor(cnt, off, 64);
  }
  if (lane == 0) { ls[w] = loss; cs[w] = cnt; }
  __syncthreads();
  if (t == 0)
    out[0] = (ls[0] + ls[1] + ls[2] + ls[3]) /
             fmaxf(cs[0] + cs[1] + cs[2] + cs[3], 1.f);
}

extern "C" void kernel_launch(void* const* d_in, const int* in_sizes, int n_in,
                              void* d_out, int out_size, void* d_ws, size_t ws_size,
                              hipStream_t stream) {
  const float* x = (const float*)d_in[0];
  const int* lab = (const int*)d_in[1];
  char* ws = (char*)d_ws;
  unsigned short* xb = (unsigned short*)ws;                 // 2 MB bf16 fragment-swizzled
  float* sq = (float*)(ws + (size_t)N * D * 2);             // 32 KB
  unsigned* posw = (unsigned*)((char*)sq + (size_t)N * 4);  // 32 KB
  unsigned* negw = posw + N;                                // 32 KB
  unsigned* hist = negw + N;                                // 32 B
  unsigned* ticket = hist + 8;                              // 4 B
  float* out = (float*)d_out;

  hipLaunchKernelGGL(k_prep, dim3(512), dim3(256), 0, stream, x, lab, xb, sq,
                     posw, negw, hist, ticket);
  hipLaunchKernelGGL(k_mine, dim3(64, 32), dim3(256), 0, stream, xb, sq, lab,
                     posw, negw, hist, ticket, out);
}

// Round 6
// 243.636 us; speedup vs baseline: 1.3929x; 1.3929x over previous
//
#include <hip/hip_runtime.h>

#define N 8192
#define D 128
#define MARGIN 0.5f
#define FLT_BIG 3.402823466e+38f
#define NBLK 2048  // k_mine grid (flat; swizzled to 64 x 32 inside)

typedef __bf16 bf16x8 __attribute__((ext_vector_type(8)));
typedef float f32x4 __attribute__((ext_vector_type(4)));
typedef unsigned short u16x8 __attribute__((ext_vector_type(8)));

__device__ __forceinline__ unsigned short f2bf_rne(float f) {
  unsigned u = __float_as_uint(f);
  u += 0x7FFFu + ((u >> 16) & 1u);  // round-to-nearest-even (inputs finite)
  return (unsigned short)(u >> 16);
}

// xb layout: MFMA-fragment-major. frag[tile][k][lane][8] ushorts, where
// tile = row>>4, lane = quad*16 + (row&15), chunk (4k+quad) = row bytes
// [k*64 + quad*16 .. +16). A and B fragments of the Gram matmul share this
// exact formula, so every fragment load is base + lane*16B (fully coalesced).
#define FRAG_OFF(tile, k, lane) ((size_t)(tile) * 2048 + (size_t)(k) * 512 + (size_t)(lane) * 8)

// ---------------- K1: fp32->bf16 fragment-swizzle + row norms + init ----------
// grid 512 x 256: thread = (row, chunk c): 16 rows/block, 16 chunks/row.
__global__ void k_prep(const float* __restrict__ x, const int* __restrict__ lab,
                       unsigned short* __restrict__ xb, float* __restrict__ sq,
                       unsigned* __restrict__ posw, unsigned* __restrict__ negw,
                       unsigned* __restrict__ hist, unsigned* __restrict__ ticket) {
  const int t = threadIdx.x;
  const int row = blockIdx.x * 16 + (t >> 4);
  const int c = t & 15;
  const float4 v0 = ((const float4*)x)[row * 32 + c * 2];
  const float4 v1 = ((const float4*)x)[row * 32 + c * 2 + 1];
  u16x8 o;
  o[0] = f2bf_rne(v0.x); o[1] = f2bf_rne(v0.y);
  o[2] = f2bf_rne(v0.z); o[3] = f2bf_rne(v0.w);
  o[4] = f2bf_rne(v1.x); o[5] = f2bf_rne(v1.y);
  o[6] = f2bf_rne(v1.z); o[7] = f2bf_rne(v1.w);
  // chunk c -> k = c>>2, quad = c&3; lane = quad*16 + (row&15)
  *(u16x8*)(xb + FRAG_OFF(row >> 4, c >> 2, ((c & 3) * 16) + (row & 15))) = o;
  float s = v0.x * v0.x + v0.y * v0.y + v0.z * v0.z + v0.w * v0.w +
            v1.x * v1.x + v1.y * v1.y + v1.z * v1.z + v1.w * v1.w;
#pragma unroll
  for (int off = 1; off < 16; off <<= 1) s += __shfl_xor(s, off, 64);
  if (c == 0) {
    sq[row] = s;
    posw[row] = 0u;           // max(d2) accumulator
    negw[row] = 0x7F800000u;  // min(d2) accumulator = +inf
  }

  if (blockIdx.x == 0) {  // label histogram
    __shared__ unsigned h[8];
    if (t < 8) h[t] = 0u;
    __syncthreads();
    unsigned long long cA = 0ull, cB = 0ull;  // 4x16-bit packed counters each
#pragma unroll
    for (int it = 0; it < 32; ++it) {
      const int l = lab[t + it * 256] & 7;
      if (l < 4) cA += 1ull << (l * 16);
      else       cB += 1ull << ((l - 4) * 16);
    }
#pragma unroll
    for (int off = 1; off < 64; off <<= 1) {
      cA += __shfl_xor(cA, off, 64);
      cB += __shfl_xor(cB, off, 64);
    }
    if ((t & 63) == 0) {
#pragma unroll
      for (int q = 0; q < 4; ++q) {
        atomicAdd(&h[q],     (unsigned)((cA >> (q * 16)) & 0xFFFFu));
        atomicAdd(&h[4 + q], (unsigned)((cB >> (q * 16)) & 0xFFFFu));
      }
    }
    __syncthreads();
    if (t < 8) hist[t] = h[t];
    if (t == 0) ticket[0] = 0u;
  }
}

// ---------------- K2: fused GEMM + mining + tail (no LDS in loop, no barriers) --
// Flat grid 2048, swizzled so CO-RESIDENT BLOCKS SHARE THE SAME j-TILE:
// dispatch hands bids round-robin across CUs (bid = c, c+256, ...), so
//   bx = (bid>>8)*8 + (bid&7),  by = (bid>>3)&31   (bijective 64x32)
// gives every block on CU c the same by -> the CU's 16 waves stream the SAME
// 4KB B-tile per js (first wave warms L1, rest hit L1 ~short latency), and
// both 8-block rounds on a CU reuse the same 64KB B-column.
// Session lessons: R1 latency-bound (all pipes <20%); R2 waves/EU=8 spills;
// R3 depth-2 reg pipeline = best (37.8us); R4 LDS staging catastrophic
// (barrier vmcnt(0) drain); R5 depth-3 spills (VGPR 64 + 124MB scratch).
// -> Depth-2 at waves/EU=4 is the no-spill frontier; attack LATENCY via
// L1 sharing (swizzle) instead of more in-flight depth.
// Self-term i==j contributes d2~bf16-noise to pos; true hardest positive is
// O(100) here and singleton classes are masked by hist validity -> no diag test.
__global__ __launch_bounds__(256, 4) void k_mine(
    const unsigned short* __restrict__ xb, const float* __restrict__ sq,
    const int* __restrict__ lab, unsigned* __restrict__ posw, unsigned* __restrict__ negw,
    const unsigned* __restrict__ hist, unsigned* __restrict__ ticket,
    float* __restrict__ out) {
  __shared__ float ls[4], cs[4];
  __shared__ unsigned lastf;

  const int t = threadIdx.x;
  const int w = t >> 6;
  const int lane = t & 63;
  const int col = lane & 15;   // MFMA m/n selector
  const int quad = lane >> 4;  // MFMA k-group / C row group

  const int bid = blockIdx.x;
  const int bx = ((bid >> 8) << 3) | (bid & 7);  // 0..63
  const int by = (bid >> 3) & 31;                // 0..31, constant per CU slot
  const int i0 = bx * 128 + w * 32;
  const int jbase = by * 256;

  // A fragments resident: 2 i-subtiles x 4 k-steps (coalesced loads)
  bf16x8 a[2][4];
#pragma unroll
  for (int is = 0; is < 2; ++is)
#pragma unroll
    for (int k = 0; k < 4; ++k)
      a[is][k] = *(const bf16x8*)(xb + FRAG_OFF((i0 >> 4) + is, k, lane));

  int labi[2][4];
#pragma unroll
  for (int is = 0; is < 2; ++is)
#pragma unroll
    for (int r = 0; r < 4; ++r) labi[is][r] = lab[i0 + is * 16 + quad * 4 + r];

  float pos[2][4], neg[2][4];
#pragma unroll
  for (int is = 0; is < 2; ++is)
#pragma unroll
    for (int r = 0; r < 4; ++r) { pos[is][r] = -FLT_BIG; neg[is][r] = FLT_BIG; }

  const float* sqp = sq + jbase + col;
  const int* labp = lab + jbase + col;
  const unsigned short* gb = xb + FRAG_OFF(jbase >> 4, 0, lane);

  bf16x8 b0A, b1A, b2A, b3A, b0B, b1B, b2B, b3B;
  float sqjA, sqjB;
  int labjA, labjB;

#define LOADB(S, js_) do {                                        \
    const unsigned short* g = gb + (size_t)(js_) * 2048;          \
    b0##S = *(const bf16x8*)(g);                                  \
    b1##S = *(const bf16x8*)(g + 512);                            \
    b2##S = *(const bf16x8*)(g + 1024);                           \
    b3##S = *(const bf16x8*)(g + 1536);                           \
    sqj##S = sqp[(js_) * 16];                                     \
    labj##S = labp[(js_) * 16];                                   \
  } while (0)

#define COMPUTE(S) do {                                                        \
    f32x4 acc0 = {0.f, 0.f, 0.f, 0.f}, acc1 = {0.f, 0.f, 0.f, 0.f};           \
    acc0 = __builtin_amdgcn_mfma_f32_16x16x32_bf16(a[0][0], b0##S, acc0, 0, 0, 0); \
    acc1 = __builtin_amdgcn_mfma_f32_16x16x32_bf16(a[1][0], b0##S, acc1, 0, 0, 0); \
    acc0 = __builtin_amdgcn_mfma_f32_16x16x32_bf16(a[0][1], b1##S, acc0, 0, 0, 0); \
    acc1 = __builtin_amdgcn_mfma_f32_16x16x32_bf16(a[1][1], b1##S, acc1, 0, 0, 0); \
    acc0 = __builtin_amdgcn_mfma_f32_16x16x32_bf16(a[0][2], b2##S, acc0, 0, 0, 0); \
    acc1 = __builtin_amdgcn_mfma_f32_16x16x32_bf16(a[1][2], b2##S, acc1, 0, 0, 0); \
    acc0 = __builtin_amdgcn_mfma_f32_16x16x32_bf16(a[0][3], b3##S, acc0, 0, 0, 0); \
    acc1 = __builtin_amdgcn_mfma_f32_16x16x32_bf16(a[1][3], b3##S, acc1, 0, 0, 0); \
    _Pragma("unroll")                                                          \
    for (int r = 0; r < 4; ++r) {                                              \
      const float m0 = fmaf(-2.f, acc0[r], sqj##S);                            \
      const float m1 = fmaf(-2.f, acc1[r], sqj##S);                            \
      const bool s0 = (labi[0][r] == labj##S);                                 \
      const bool s1 = (labi[1][r] == labj##S);                                 \
      pos[0][r] = fmaxf(pos[0][r], s0 ? m0 : -FLT_BIG);                        \
      neg[0][r] = fminf(neg[0][r], s0 ? FLT_BIG : m0);                         \
      pos[1][r] = fmaxf(pos[1][r], s1 ? m1 : -FLT_BIG);                        \
      neg[1][r] = fminf(neg[1][r], s1 ? FLT_BIG : m1);                         \
    }                                                                          \
  } while (0)

  // depth-2 pipeline (R3-proven, no spill): A holds js, B holds js+1.
  LOADB(A, 0);
#pragma unroll 1
  for (int js = 0; js < 14; js += 2) {
    LOADB(B, js + 1);
    COMPUTE(A);
    LOADB(A, js + 2);
    COMPUTE(B);
  }
  LOADB(B, 15);
  COMPUTE(A);  // js = 14
  COMPUTE(B);  // js = 15

#undef LOADB
#undef COMPUTE

  // reduce the 16 cols sharing each i-row, add sq_i back, combine via atomics
#pragma unroll
  for (int is = 0; is < 2; ++is)
#pragma unroll
    for (int r = 0; r < 4; ++r) {
      float p = pos[is][r], n = neg[is][r];
#pragma unroll
      for (int off = 1; off < 16; off <<= 1) {
        p = fmaxf(p, __shfl_xor(p, off, 64));
        n = fminf(n, __shfl_xor(n, off, 64));
      }
      if (col == 0) {
        const int i = i0 + is * 16 + quad * 4 + r;
        const float sqi = sq[i];
        atomicMax(posw + i, __float_as_uint(fmaxf(sqi + p, 0.f)));
        atomicMin(negw + i, __float_as_uint(fmaxf(sqi + n, 0.f)));
      }
    }

  // ---- fused tail: last block (ticket) computes the final loss
  // (this exact path passed with absmax 0.0 in R4 and R5)
  __syncthreads();   // all this block's mining atomics issued & drained
  __threadfence();   // make them device-visible before the ticket
  if (t == 0) lastf = (atomicAdd(ticket, 1u) == (unsigned)(NBLK - 1)) ? 1u : 0u;
  __syncthreads();
  if (!lastf) return;

  float loss = 0.f, cnt = 0.f;
#pragma unroll 4
  for (int it = 0; it < 32; ++it) {
    const int i = t + it * 256;
    const float pd2 = __uint_as_float(
        __hip_atomic_load(posw + i, __ATOMIC_RELAXED, __HIP_MEMORY_SCOPE_AGENT));
    const float nd2 = __uint_as_float(
        __hip_atomic_load(negw + i, __ATOMIC_RELAXED, __HIP_MEMORY_SCOPE_AGENT));
    const unsigned c = hist[lab[i] & 7];
    if (c >= 2u && c < (unsigned)N) {
      loss += fmaxf(sqrtf(pd2) - sqrtf(fminf(nd2, FLT_BIG)) + MARGIN, 0.f);
      cnt += 1.f;
    }
  }
#pragma unroll
  for (int off = 1; off < 64; off <<= 1) {
    loss += __shfl_xor(loss, off, 64);
    cnt += __shfl_xor(cnt, off, 64);
  }
  if (lane == 0) { ls[w] = loss; cs[w] = cnt; }
  __syncthreads();
  if (t == 0)
    out[0] = (ls[0] + ls[1] + ls[2] + ls[3]) /
             fmaxf(cs[0] + cs[1] + cs[2] + cs[3], 1.f);
}

extern "C" void kernel_launch(void* const* d_in, const int* in_sizes, int n_in,
                              void* d_out, int out_size, void* d_ws, size_t ws_size,
                              hipStream_t stream) {
  const float* x = (const float*)d_in[0];
  const int* lab = (const int*)d_in[1];
  char* ws = (char*)d_ws;
  unsigned short* xb = (unsigned short*)ws;                 // 2 MB bf16 fragment-swizzled
  float* sq = (float*)(ws + (size_t)N * D * 2);             // 32 KB
  unsigned* posw = (unsigned*)((char*)sq + (size_t)N * 4);  // 32 KB
  unsigned* negw = posw + N;                                // 32 KB
  unsigned* hist = negw + N;                                // 32 B
  unsigned* ticket = hist + 8;                              // 4 B
  float* out = (float*)d_out;

  hipLaunchKernelGGL(k_prep, dim3(512), dim3(256), 0, stream, x, lab, xb, sq,
                     posw, negw, hist, ticket);
  hipLaunchKernelGGL(k_mine, dim3(NBLK), dim3(256), 0, stream, xb, sq, lab,
                     posw, negw, hist, ticket, out);
}

// Round 7
// 102.358 us; speedup vs baseline: 3.3153x; 2.3802x over previous
//
#include <hip/hip_runtime.h>

#define N 8192
#define D 128
#define MARGIN 0.5f
#define FLT_BIG 3.402823466e+38f
#define NBLK 2048  // k_mine flat grid (swizzled to 64 x 32 inside)

typedef __bf16 bf16x8 __attribute__((ext_vector_type(8)));
typedef float f32x4 __attribute__((ext_vector_type(4)));
typedef unsigned short u16x8 __attribute__((ext_vector_type(8)));

__device__ __forceinline__ unsigned short f2bf_rne(float f) {
  unsigned u = __float_as_uint(f);
  u += 0x7FFFu + ((u >> 16) & 1u);  // round-to-nearest-even (inputs finite)
  return (unsigned short)(u >> 16);
}

// xb layout: MFMA-fragment-major. frag[tile][k][lane][8] ushorts, where
// tile = row>>4, lane = quad*16 + (row&15), chunk (4k+quad) = row bytes
// [k*64 + quad*16 .. +16). A and B fragments of the Gram matmul share this
// exact formula, so every fragment load is base + lane*16B (fully coalesced).
#define FRAG_OFF(tile, k, lane) ((size_t)(tile) * 2048 + (size_t)(k) * 512 + (size_t)(lane) * 8)

// ---------------- K1: fp32->bf16 fragment-swizzle + row norms + init ----------
// grid 512 x 256: thread = (row, chunk c): 16 rows/block, 16 chunks/row.
__global__ void k_prep(const float* __restrict__ x, const int* __restrict__ lab,
                       unsigned short* __restrict__ xb, float* __restrict__ sq,
                       unsigned* __restrict__ posw, unsigned* __restrict__ negw,
                       unsigned* __restrict__ hist, float* __restrict__ acc,
                       unsigned* __restrict__ ticket) {
  const int t = threadIdx.x;
  const int row = blockIdx.x * 16 + (t >> 4);
  const int c = t & 15;
  const float4 v0 = ((const float4*)x)[row * 32 + c * 2];
  const float4 v1 = ((const float4*)x)[row * 32 + c * 2 + 1];
  u16x8 o;
  o[0] = f2bf_rne(v0.x); o[1] = f2bf_rne(v0.y);
  o[2] = f2bf_rne(v0.z); o[3] = f2bf_rne(v0.w);
  o[4] = f2bf_rne(v1.x); o[5] = f2bf_rne(v1.y);
  o[6] = f2bf_rne(v1.z); o[7] = f2bf_rne(v1.w);
  // chunk c -> k = c>>2, quad = c&3; lane = quad*16 + (row&15)
  *(u16x8*)(xb + FRAG_OFF(row >> 4, c >> 2, ((c & 3) * 16) + (row & 15))) = o;
  float s = v0.x * v0.x + v0.y * v0.y + v0.z * v0.z + v0.w * v0.w +
            v1.x * v1.x + v1.y * v1.y + v1.z * v1.z + v1.w * v1.w;
#pragma unroll
  for (int off = 1; off < 16; off <<= 1) s += __shfl_xor(s, off, 64);
  if (c == 0) {
    sq[row] = s;
    posw[row] = 0u;           // max(d2) accumulator
    negw[row] = 0x7F800000u;  // min(d2) accumulator = +inf
  }

  if (blockIdx.x == 0) {  // label histogram
    __shared__ unsigned h[8];
    if (t < 8) h[t] = 0u;
    __syncthreads();
    unsigned long long cA = 0ull, cB = 0ull;  // 4x16-bit packed counters each
#pragma unroll
    for (int it = 0; it < 32; ++it) {
      const int l = lab[t + it * 256] & 7;
      if (l < 4) cA += 1ull << (l * 16);
      else       cB += 1ull << ((l - 4) * 16);
    }
#pragma unroll
    for (int off = 1; off < 64; off <<= 1) {
      cA += __shfl_xor(cA, off, 64);
      cB += __shfl_xor(cB, off, 64);
    }
    if ((t & 63) == 0) {
#pragma unroll
      for (int q = 0; q < 4; ++q) {
        atomicAdd(&h[q],     (unsigned)((cA >> (q * 16)) & 0xFFFFu));
        atomicAdd(&h[4 + q], (unsigned)((cB >> (q * 16)) & 0xFFFFu));
      }
    }
    __syncthreads();
    if (t < 8) hist[t] = h[t];
    if (t == 0) { acc[0] = 0.f; acc[1] = 0.f; ticket[0] = 0u; }
  }
}

// ---------------- K2: fused GEMM + hardest-pos/neg mining (no LDS, no barriers,
// NO per-block threadfence) -------------------------------------------------
// Session lessons: R1 latency-bound (all pipes <20%); R2 waves/EU=8 spills;
// R3 depth-2 reg pipeline best (k_mine ~38us, total 100.2); R4/R6 fused-tail
// per-block __threadfence = ~183us floor (2048 agent-scope release fences
// invalidate the cached xb stream; R4 and R6 identical despite different
// loops); R5 depth-3 spills (VGPR 64 + 124MB scratch).
// -> structure: EXACT R3 (separate k_tail, 32 fences there), depth-2,
// waves/EU=4. ONE isolated change this round: CU-residency block swizzle.
// Flat grid 2048; bid->CU is (empirically) round-robin, so blocks congruent
// mod 256 co-reside on one CU. by=(bid>>3)&31 is invariant under bid+256
// (+256 -> +32 in bid>>3, wrapped by &31), so all 4 resident blocks share the
// same j-column: 16 waves stream the SAME 4KB B-tile per js (L1 hits after
// first wave; depth-2 covers L1 latency), and both 4-block rounds on a CU
// reuse the same 64KB B-column. bx=(bid>>8)*8+(bid&7) keeps it bijective.
// Self-term i==j contributes d2~bf16-noise to pos; true hardest positive is
// O(100) here and singleton classes are masked by hist validity -> no diag test.
__global__ __launch_bounds__(256, 4) void k_mine(
    const unsigned short* __restrict__ xb, const float* __restrict__ sq,
    const int* __restrict__ lab, unsigned* __restrict__ posw, unsigned* __restrict__ negw) {
  const int t = threadIdx.x;
  const int w = t >> 6;
  const int lane = t & 63;
  const int col = lane & 15;   // MFMA m/n selector
  const int quad = lane >> 4;  // MFMA k-group / C row group

  const int bid = blockIdx.x;
  const int bx = ((bid >> 8) << 3) | (bid & 7);  // 0..63
  const int by = (bid >> 3) & 31;                // 0..31, same for co-resident blocks
  const int i0 = bx * 128 + w * 32;
  const int jbase = by * 256;

  // A fragments resident: 2 i-subtiles x 4 k-steps (coalesced loads)
  bf16x8 a[2][4];
#pragma unroll
  for (int is = 0; is < 2; ++is)
#pragma unroll
    for (int k = 0; k < 4; ++k)
      a[is][k] = *(const bf16x8*)(xb + FRAG_OFF((i0 >> 4) + is, k, lane));

  int labi[2][4];
#pragma unroll
  for (int is = 0; is < 2; ++is)
#pragma unroll
    for (int r = 0; r < 4; ++r) labi[is][r] = lab[i0 + is * 16 + quad * 4 + r];

  float pos[2][4], neg[2][4];
#pragma unroll
  for (int is = 0; is < 2; ++is)
#pragma unroll
    for (int r = 0; r < 4; ++r) { pos[is][r] = -FLT_BIG; neg[is][r] = FLT_BIG; }

  const float* sqp = sq + jbase + col;
  const int* labp = lab + jbase + col;
  const unsigned short* gb = xb + FRAG_OFF(jbase >> 4, 0, lane);

  bf16x8 b0A, b1A, b2A, b3A, b0B, b1B, b2B, b3B;
  float sqjA, sqjB;
  int labjA, labjB;

#define LOADB(S, js_) do {                                        \
    const unsigned short* g = gb + (size_t)(js_) * 2048;          \
    b0##S = *(const bf16x8*)(g);                                  \
    b1##S = *(const bf16x8*)(g + 512);                            \
    b2##S = *(const bf16x8*)(g + 1024);                           \
    b3##S = *(const bf16x8*)(g + 1536);                           \
    sqj##S = sqp[(js_) * 16];                                     \
    labj##S = labp[(js_) * 16];                                   \
  } while (0)

#define COMPUTE(S) do {                                                        \
    f32x4 acc0 = {0.f, 0.f, 0.f, 0.f}, acc1 = {0.f, 0.f, 0.f, 0.f};           \
    acc0 = __builtin_amdgcn_mfma_f32_16x16x32_bf16(a[0][0], b0##S, acc0, 0, 0, 0); \
    acc1 = __builtin_amdgcn_mfma_f32_16x16x32_bf16(a[1][0], b0##S, acc1, 0, 0, 0); \
    acc0 = __builtin_amdgcn_mfma_f32_16x16x32_bf16(a[0][1], b1##S, acc0, 0, 0, 0); \
    acc1 = __builtin_amdgcn_mfma_f32_16x16x32_bf16(a[1][1], b1##S, acc1, 0, 0, 0); \
    acc0 = __builtin_amdgcn_mfma_f32_16x16x32_bf16(a[0][2], b2##S, acc0, 0, 0, 0); \
    acc1 = __builtin_amdgcn_mfma_f32_16x16x32_bf16(a[1][2], b2##S, acc1, 0, 0, 0); \
    acc0 = __builtin_amdgcn_mfma_f32_16x16x32_bf16(a[0][3], b3##S, acc0, 0, 0, 0); \
    acc1 = __builtin_amdgcn_mfma_f32_16x16x32_bf16(a[1][3], b3##S, acc1, 0, 0, 0); \
    _Pragma("unroll")                                                          \
    for (int r = 0; r < 4; ++r) {                                              \
      const float m0 = fmaf(-2.f, acc0[r], sqj##S);                            \
      const float m1 = fmaf(-2.f, acc1[r], sqj##S);                            \
      const bool s0 = (labi[0][r] == labj##S);                                 \
      const bool s1 = (labi[1][r] == labj##S);                                 \
      pos[0][r] = fmaxf(pos[0][r], s0 ? m0 : -FLT_BIG);                        \
      neg[0][r] = fminf(neg[0][r], s0 ? FLT_BIG : m0);                         \
      pos[1][r] = fmaxf(pos[1][r], s1 ? m1 : -FLT_BIG);                        \
      neg[1][r] = fminf(neg[1][r], s1 ? FLT_BIG : m1);                         \
    }                                                                          \
  } while (0)

  // depth-2 pipeline (R3-proven, no spill): A holds js, B holds js+1.
  LOADB(A, 0);
#pragma unroll 1
  for (int js = 0; js < 14; js += 2) {
    LOADB(B, js + 1);
    COMPUTE(A);
    LOADB(A, js + 2);
    COMPUTE(B);
  }
  LOADB(B, 15);
  COMPUTE(A);  // js = 14
  COMPUTE(B);  // js = 15

#undef LOADB
#undef COMPUTE

  // reduce the 16 cols sharing each i-row, add sq_i back, combine via atomics
#pragma unroll
  for (int is = 0; is < 2; ++is)
#pragma unroll
    for (int r = 0; r < 4; ++r) {
      float p = pos[is][r], n = neg[is][r];
#pragma unroll
      for (int off = 1; off < 16; off <<= 1) {
        p = fmaxf(p, __shfl_xor(p, off, 64));
        n = fminf(n, __shfl_xor(n, off, 64));
      }
      if (col == 0) {
        const int i = i0 + is * 16 + quad * 4 + r;
        const float sqi = sq[i];
        atomicMax(posw + i, __float_as_uint(fmaxf(sqi + p, 0.f)));
        atomicMin(negw + i, __float_as_uint(fmaxf(sqi + n, 0.f)));
      }
    }
}

// ---------------- K3: per-row loss + global reduce + finalize (ticketed) -----
__global__ void k_tail(const unsigned* __restrict__ posw, const unsigned* __restrict__ negw,
                       const int* __restrict__ lab, const unsigned* __restrict__ hist,
                       float* __restrict__ acc, unsigned* __restrict__ ticket,
                       float* __restrict__ out) {
  __shared__ float ls[4], cs[4];
  const int t = threadIdx.x;
  const int i = blockIdx.x * 256 + t;
  const float pd2 = __uint_as_float(posw[i]);
  const float nd2 = __uint_as_float(negw[i]);
  const unsigned cnt = hist[lab[i] & 7];
  const bool valid = (cnt >= 2u) && (cnt < (unsigned)N);
  float loss = 0.f, c = 0.f;
  if (valid) {
    loss = fmaxf(sqrtf(pd2) - sqrtf(fminf(nd2, FLT_BIG)) + MARGIN, 0.f);
    c = 1.f;
  }
#pragma unroll
  for (int off = 1; off < 64; off <<= 1) {
    loss += __shfl_xor(loss, off, 64);
    c += __shfl_xor(c, off, 64);
  }
  const int wv = t >> 6;
  if ((t & 63) == 0) { ls[wv] = loss; cs[wv] = c; }
  __syncthreads();
  if (t == 0) {
    atomicAdd(acc + 0, ls[0] + ls[1] + ls[2] + ls[3]);
    atomicAdd(acc + 1, cs[0] + cs[1] + cs[2] + cs[3]);
    __threadfence();
    const unsigned tk = atomicAdd(ticket, 1u);
    if (tk == 31u) {  // last block: partials fenced-in; read via atomics (coherent)
      const float lsum = atomicAdd(acc + 0, 0.f);
      const float csum = atomicAdd(acc + 1, 0.f);
      out[0] = lsum / fmaxf(csum, 1.f);
    }
  }
}

extern "C" void kernel_launch(void* const* d_in, const int* in_sizes, int n_in,
                              void* d_out, int out_size, void* d_ws, size_t ws_size,
                              hipStream_t stream) {
  const float* x = (const float*)d_in[0];
  const int* lab = (const int*)d_in[1];
  char* ws = (char*)d_ws;
  unsigned short* xb = (unsigned short*)ws;                 // 2 MB bf16 fragment-swizzled
  float* sq = (float*)(ws + (size_t)N * D * 2);             // 32 KB
  unsigned* posw = (unsigned*)((char*)sq + (size_t)N * 4);  // 32 KB
  unsigned* negw = posw + N;                                // 32 KB
  unsigned* hist = negw + N;                                // 32 B
  unsigned* ticket = hist + 8;                              // 4 B
  float* acc = (float*)(ticket + 1);                        // 8 B
  float* out = (float*)d_out;

  hipLaunchKernelGGL(k_prep, dim3(512), dim3(256), 0, stream, x, lab, xb, sq,
                     posw, negw, hist, acc, ticket);
  hipLaunchKernelGGL(k_mine, dim3(NBLK), dim3(256), 0, stream, xb, sq, lab, posw, negw);
  hipLaunchKernelGGL(k_tail, dim3(32), dim3(256), 0, stream, posw, negw, lab, hist,
                     acc, ticket, out);
}

// Round 8
// 102.081 us; speedup vs baseline: 3.3243x; 1.0027x over previous
//
#include <hip/hip_runtime.h>

#define N 8192
#define D 128
#define MARGIN 0.5f
#define FLT_BIG 3.402823466e+38f

typedef __bf16 bf16x8 __attribute__((ext_vector_type(8)));
typedef float f32x4 __attribute__((ext_vector_type(4)));
typedef unsigned short u16x8 __attribute__((ext_vector_type(8)));

__device__ __forceinline__ unsigned short f2bf_rne(float f) {
  unsigned u = __float_as_uint(f);
  u += 0x7FFFu + ((u >> 16) & 1u);  // round-to-nearest-even (inputs finite)
  return (unsigned short)(u >> 16);
}

// xb layout: MFMA-fragment-major. frag[tile][k][lane][8] ushorts, where
// tile = row>>4, lane = quad*16 + (row&15), chunk (4k+quad) = row bytes
// [k*64 + quad*16 .. +16). A and B fragments of the Gram matmul share this
// exact formula, so every fragment load is base + lane*16B (fully coalesced).
#define FRAG_OFF(tile, k, lane) ((size_t)(tile) * 2048 + (size_t)(k) * 512 + (size_t)(lane) * 8)

// ---------------- K1: fp32->bf16 fragment-swizzle + row norms + init ----------
// grid 512 x 256: thread = (row, chunk c): 16 rows/block, 16 chunks/row.
__global__ void k_prep(const float* __restrict__ x, const int* __restrict__ lab,
                       unsigned short* __restrict__ xb, float* __restrict__ sq,
                       unsigned* __restrict__ posw, unsigned* __restrict__ negw,
                       unsigned* __restrict__ hist, float* __restrict__ acc,
                       unsigned* __restrict__ ticket) {
  const int t = threadIdx.x;
  const int row = blockIdx.x * 16 + (t >> 4);
  const int c = t & 15;
  const float4 v0 = ((const float4*)x)[row * 32 + c * 2];
  const float4 v1 = ((const float4*)x)[row * 32 + c * 2 + 1];
  u16x8 o;
  o[0] = f2bf_rne(v0.x); o[1] = f2bf_rne(v0.y);
  o[2] = f2bf_rne(v0.z); o[3] = f2bf_rne(v0.w);
  o[4] = f2bf_rne(v1.x); o[5] = f2bf_rne(v1.y);
  o[6] = f2bf_rne(v1.z); o[7] = f2bf_rne(v1.w);
  // chunk c -> k = c>>2, quad = c&3; lane = quad*16 + (row&15)
  *(u16x8*)(xb + FRAG_OFF(row >> 4, c >> 2, ((c & 3) * 16) + (row & 15))) = o;
  float s = v0.x * v0.x + v0.y * v0.y + v0.z * v0.z + v0.w * v0.w +
            v1.x * v1.x + v1.y * v1.y + v1.z * v1.z + v1.w * v1.w;
#pragma unroll
  for (int off = 1; off < 16; off <<= 1) s += __shfl_xor(s, off, 64);
  if (c == 0) {
    sq[row] = s;
    posw[row] = 0u;           // max(d2) accumulator
    negw[row] = 0x7F800000u;  // min(d2) accumulator = +inf
  }

  if (blockIdx.x == 0) {  // label histogram
    __shared__ unsigned h[8];
    if (t < 8) h[t] = 0u;
    __syncthreads();
    unsigned long long cA = 0ull, cB = 0ull;  // 4x16-bit packed counters each
#pragma unroll
    for (int it = 0; it < 32; ++it) {
      const int l = lab[t + it * 256] & 7;
      if (l < 4) cA += 1ull << (l * 16);
      else       cB += 1ull << ((l - 4) * 16);
    }
#pragma unroll
    for (int off = 1; off < 64; off <<= 1) {
      cA += __shfl_xor(cA, off, 64);
      cB += __shfl_xor(cB, off, 64);
    }
    if ((t & 63) == 0) {
#pragma unroll
      for (int q = 0; q < 4; ++q) {
        atomicAdd(&h[q],     (unsigned)((cA >> (q * 16)) & 0xFFFFu));
        atomicAdd(&h[4 + q], (unsigned)((cB >> (q * 16)) & 0xFFFFu));
      }
    }
    __syncthreads();
    if (t < 8) hist[t] = h[t];
    if (t == 0) { acc[0] = 0.f; acc[1] = 0.f; ticket[0] = 0u; }
  }
}

// ---------------- K2: fused GEMM + mining, cross-js MFMA/MINE pipeline --------
// grid (64,32) x 256thr (plain R3 mapping; R7 proved swizzle neutral).
// Session lessons: R1 latency-bound (all pipes <20%); R2/R5/R6 spills were the
// ALLOCATOR choosing 64 regs (8 w/EU) + scratch under a 128 cap ->
// amdgpu_waves_per_eu(4,4) pins the allocation target; R3 depth-2 loads best
// (k_mine ~38us); R4/R6 per-block __threadfence ~183us floor (banned); R7
// CU-residency swizzle neutral -> B traffic/L1 not binding. Residual theory:
// per-js serial chain [4-deep MFMA chain ~100cy -> mine ~20cy deep] x 16 js,
// only partly hidden by 4-wave TLP.
// This round: SPLIT compute into MFMA-only (acc sets P/Q) and MINE, pipelined
// ONE TILE APART: mine(js) runs while mfma(js+1) is in flight (separate
// pipes). Named sets only (static indexing); meta (sqj/labj) double-buffered
// with its acc set, loaded AFTER the mine that frees it.
// Self-term i==j contributes d2~bf16-noise to pos; true hardest positive is
// O(100) here and singleton classes are masked by hist validity -> no diag test.
__global__ __launch_bounds__(256)
__attribute__((amdgpu_waves_per_eu(4, 4)))
void k_mine(
    const unsigned short* __restrict__ xb, const float* __restrict__ sq,
    const int* __restrict__ lab, unsigned* __restrict__ posw, unsigned* __restrict__ negw) {
  const int t = threadIdx.x;
  const int w = t >> 6;
  const int lane = t & 63;
  const int col = lane & 15;   // MFMA m/n selector
  const int quad = lane >> 4;  // MFMA k-group / C row group
  const int i0 = blockIdx.x * 128 + w * 32;
  const int jbase = blockIdx.y * 256;

  // A fragments resident: 2 i-subtiles x 4 k-steps (coalesced loads)
  bf16x8 a[2][4];
#pragma unroll
  for (int is = 0; is < 2; ++is)
#pragma unroll
    for (int k = 0; k < 4; ++k)
      a[is][k] = *(const bf16x8*)(xb + FRAG_OFF((i0 >> 4) + is, k, lane));

  int labi[2][4];
#pragma unroll
  for (int is = 0; is < 2; ++is)
#pragma unroll
    for (int r = 0; r < 4; ++r) labi[is][r] = lab[i0 + is * 16 + quad * 4 + r];

  float pos[2][4], neg[2][4];
#pragma unroll
  for (int is = 0; is < 2; ++is)
#pragma unroll
    for (int r = 0; r < 4; ++r) { pos[is][r] = -FLT_BIG; neg[is][r] = FLT_BIG; }

  const float* sqp = sq + jbase + col;
  const int* labp = lab + jbase + col;
  const unsigned short* gb = xb + FRAG_OFF(jbase >> 4, 0, lane);

  // B fragment double buffer (A->acc set P, B->acc set Q, fixed pairing)
  bf16x8 b0A, b1A, b2A, b3A, b0B, b1B, b2B, b3B;
  f32x4 acc0P, acc1P, acc0Q, acc1Q;
  float sqjP, sqjQ;
  int labjP, labjQ;

#define LOADB(S, js_) do {                                        \
    const unsigned short* g = gb + (size_t)(js_) * 2048;          \
    b0##S = *(const bf16x8*)(g);                                  \
    b1##S = *(const bf16x8*)(g + 512);                            \
    b2##S = *(const bf16x8*)(g + 1024);                           \
    b3##S = *(const bf16x8*)(g + 1536);                           \
  } while (0)

#define LOADM(S, js_) do {                                        \
    sqj##S = sqp[(js_) * 16];                                     \
    labj##S = labp[(js_) * 16];                                   \
  } while (0)

#define MFMA8(BUF, S) do {                                                     \
    acc0##S = (f32x4){0.f, 0.f, 0.f, 0.f};                                     \
    acc1##S = (f32x4){0.f, 0.f, 0.f, 0.f};                                     \
    acc0##S = __builtin_amdgcn_mfma_f32_16x16x32_bf16(a[0][0], b0##BUF, acc0##S, 0, 0, 0); \
    acc1##S = __builtin_amdgcn_mfma_f32_16x16x32_bf16(a[1][0], b0##BUF, acc1##S, 0, 0, 0); \
    acc0##S = __builtin_amdgcn_mfma_f32_16x16x32_bf16(a[0][1], b1##BUF, acc0##S, 0, 0, 0); \
    acc1##S = __builtin_amdgcn_mfma_f32_16x16x32_bf16(a[1][1], b1##BUF, acc1##S, 0, 0, 0); \
    acc0##S = __builtin_amdgcn_mfma_f32_16x16x32_bf16(a[0][2], b2##BUF, acc0##S, 0, 0, 0); \
    acc1##S = __builtin_amdgcn_mfma_f32_16x16x32_bf16(a[1][2], b2##BUF, acc1##S, 0, 0, 0); \
    acc0##S = __builtin_amdgcn_mfma_f32_16x16x32_bf16(a[0][3], b3##BUF, acc0##S, 0, 0, 0); \
    acc1##S = __builtin_amdgcn_mfma_f32_16x16x32_bf16(a[1][3], b3##BUF, acc1##S, 0, 0, 0); \
  } while (0)

#define MINE(S) do {                                                           \
    _Pragma("unroll")                                                          \
    for (int r = 0; r < 4; ++r) {                                              \
      const float m0 = fmaf(-2.f, acc0##S[r], sqj##S);                         \
      const float m1 = fmaf(-2.f, acc1##S[r], sqj##S);                         \
      const bool s0 = (labi[0][r] == labj##S);                                 \
      const bool s1 = (labi[1][r] == labj##S);                                 \
      pos[0][r] = fmaxf(pos[0][r], s0 ? m0 : -FLT_BIG);                        \
      neg[0][r] = fminf(neg[0][r], s0 ? FLT_BIG : m0);                         \
      pos[1][r] = fmaxf(pos[1][r], s1 ? m1 : -FLT_BIG);                        \
      neg[1][r] = fminf(neg[1][r], s1 ? FLT_BIG : m1);                         \
    }                                                                          \
  } while (0)

  // Pipeline: A/P carries even tiles, B/Q odd tiles. mine(js) overlaps
  // mfma(js+1); b-loads issued ~1.5 phases ahead of use.
  LOADB(A, 0); LOADM(P, 0);
  LOADB(B, 1); LOADM(Q, 1);
  MFMA8(A, P);  // tile 0

#pragma unroll 1
  for (int js = 0; js <= 10; js += 2) {
    LOADB(A, js + 2);
    MFMA8(B, Q);       // tile js+1 (in flight during MINE below)
    MINE(P);           // tile js
    LOADM(P, js + 2);
    LOADB(B, js + 3);
    MFMA8(A, P);       // tile js+2
    MINE(Q);           // tile js+1
    LOADM(Q, js + 3);
  }
  // invariant out of loop: accP = tile 12, B holds tile 13, metaQ = 13
  LOADB(A, 14);
  MFMA8(B, Q);   // 13
  MINE(P);       // 12
  LOADM(P, 14);
  LOADB(B, 15);
  MFMA8(A, P);   // 14
  MINE(Q);       // 13
  LOADM(Q, 15);
  MFMA8(B, Q);   // 15
  MINE(P);       // 14
  MINE(Q);       // 15

#undef LOADB
#undef LOADM
#undef MFMA8
#undef MINE

  // reduce the 16 cols sharing each i-row, add sq_i back, combine via atomics
#pragma unroll
  for (int is = 0; is < 2; ++is)
#pragma unroll
    for (int r = 0; r < 4; ++r) {
      float p = pos[is][r], n = neg[is][r];
#pragma unroll
      for (int off = 1; off < 16; off <<= 1) {
        p = fmaxf(p, __shfl_xor(p, off, 64));
        n = fminf(n, __shfl_xor(n, off, 64));
      }
      if (col == 0) {
        const int i = i0 + is * 16 + quad * 4 + r;
        const float sqi = sq[i];
        atomicMax(posw + i, __float_as_uint(fmaxf(sqi + p, 0.f)));
        atomicMin(negw + i, __float_as_uint(fmaxf(sqi + n, 0.f)));
      }
    }
}

// ---------------- K3: per-row loss + global reduce + finalize (ticketed) -----
__global__ void k_tail(const unsigned* __restrict__ posw, const unsigned* __restrict__ negw,
                       const int* __restrict__ lab, const unsigned* __restrict__ hist,
                       float* __restrict__ acc, unsigned* __restrict__ ticket,
                       float* __restrict__ out) {
  __shared__ float ls[4], cs[4];
  const int t = threadIdx.x;
  const int i = blockIdx.x * 256 + t;
  const float pd2 = __uint_as_float(posw[i]);
  const float nd2 = __uint_as_float(negw[i]);
  const unsigned cnt = hist[lab[i] & 7];
  const bool valid = (cnt >= 2u) && (cnt < (unsigned)N);
  float loss = 0.f, c = 0.f;
  if (valid) {
    loss = fmaxf(sqrtf(pd2) - sqrtf(fminf(nd2, FLT_BIG)) + MARGIN, 0.f);
    c = 1.f;
  }
#pragma unroll
  for (int off = 1; off < 64; off <<= 1) {
    loss += __shfl_xor(loss, off, 64);
    c += __shfl_xor(c, off, 64);
  }
  const int wv = t >> 6;
  if ((t & 63) == 0) { ls[wv] = loss; cs[wv] = c; }
  __syncthreads();
  if (t == 0) {
    atomicAdd(acc + 0, ls[0] + ls[1] + ls[2] + ls[3]);
    atomicAdd(acc + 1, cs[0] + cs[1] + cs[2] + cs[3]);
    __threadfence();
    const unsigned tk = atomicAdd(ticket, 1u);
    if (tk == 31u) {  // last block: partials fenced-in; read via atomics (coherent)
      const float lsum = atomicAdd(acc + 0, 0.f);
      const float csum = atomicAdd(acc + 1, 0.f);
      out[0] = lsum / fmaxf(csum, 1.f);
    }
  }
}

extern "C" void kernel_launch(void* const* d_in, const int* in_sizes, int n_in,
                              void* d_out, int out_size, void* d_ws, size_t ws_size,
                              hipStream_t stream) {
  const float* x = (const float*)d_in[0];
  const int* lab = (const int*)d_in[1];
  char* ws = (char*)d_ws;
  unsigned short* xb = (unsigned short*)ws;                 // 2 MB bf16 fragment-swizzled
  float* sq = (float*)(ws + (size_t)N * D * 2);             // 32 KB
  unsigned* posw = (unsigned*)((char*)sq + (size_t)N * 4);  // 32 KB
  unsigned* negw = posw + N;                                // 32 KB
  unsigned* hist = negw + N;                                // 32 B
  unsigned* ticket = hist + 8;                              // 4 B
  float* acc = (float*)(ticket + 1);                        // 8 B
  float* out = (float*)d_out;

  hipLaunchKernelGGL(k_prep, dim3(512), dim3(256), 0, stream, x, lab, xb, sq,
                     posw, negw, hist, acc, ticket);
  hipLaunchKernelGGL(k_mine, dim3(64, 32), dim3(256), 0, stream, xb, sq, lab, posw, negw);
  hipLaunchKernelGGL(k_tail, dim3(32), dim3(256), 0, stream, posw, negw, lab, hist,
                     acc, ticket, out);
}

// Round 9
// 98.429 us; speedup vs baseline: 3.4477x; 1.0371x over previous
//
#include <hip/hip_runtime.h>

#define N 8192
#define D 128
#define MARGIN 0.5f
#define FLT_BIG 3.402823466e+38f
// Upper-triangle tiling: 128-row i-tiles x 256-col j-tiles.
// For each j-tile bj (32), i-tiles bi in [0, 2*bj+2) -> sum = 1056 blocks.
#define NBLK 1056

typedef __bf16 bf16x8 __attribute__((ext_vector_type(8)));
typedef float f32x4 __attribute__((ext_vector_type(4)));
typedef unsigned short u16x8 __attribute__((ext_vector_type(8)));

__device__ __forceinline__ unsigned short f2bf_rne(float f) {
  unsigned u = __float_as_uint(f);
  u += 0x7FFFu + ((u >> 16) & 1u);  // round-to-nearest-even (inputs finite)
  return (unsigned short)(u >> 16);
}

// order-preserving float<->uint keys (R1-verified). Untouched-slot identities:
// cposk=0 -> NaN -> fmaxf(NaN,0)=0 -> atomicMax(posw,0) no-op; every slot is
// touched anyway (each js covers all 16 of its cols in every wave).
__device__ __forceinline__ unsigned fkey(float f) {
  unsigned u = __float_as_uint(f);
  return ((int)u < 0) ? ~u : (u | 0x80000000u);
}
__device__ __forceinline__ float fkey_inv(unsigned k) {
  unsigned u = ((int)k < 0) ? (k & 0x7FFFFFFFu) : ~k;
  return __uint_as_float(u);
}

// xb layout: MFMA-fragment-major. frag[tile][k][lane][8] ushorts, where
// tile = row>>4, lane = quad*16 + (row&15), chunk (4k+quad) = row bytes
// [k*64 + quad*16 .. +16). A and B fragments of the Gram matmul share this
// exact formula, so every fragment load is base + lane*16B (fully coalesced).
#define FRAG_OFF(tile, k, lane) ((size_t)(tile) * 2048 + (size_t)(k) * 512 + (size_t)(lane) * 8)

// ---------------- K1: fp32->bf16 fragment-swizzle + row norms + init ----------
// grid 512 x 256: thread = (row, chunk c): 16 rows/block, 16 chunks/row.
__global__ void k_prep(const float* __restrict__ x, const int* __restrict__ lab,
                       unsigned short* __restrict__ xb, float* __restrict__ sq,
                       unsigned* __restrict__ posw, unsigned* __restrict__ negw,
                       unsigned* __restrict__ hist, float* __restrict__ acc,
                       unsigned* __restrict__ ticket) {
  const int t = threadIdx.x;
  const int row = blockIdx.x * 16 + (t >> 4);
  const int c = t & 15;
  const float4 v0 = ((const float4*)x)[row * 32 + c * 2];
  const float4 v1 = ((const float4*)x)[row * 32 + c * 2 + 1];
  u16x8 o;
  o[0] = f2bf_rne(v0.x); o[1] = f2bf_rne(v0.y);
  o[2] = f2bf_rne(v0.z); o[3] = f2bf_rne(v0.w);
  o[4] = f2bf_rne(v1.x); o[5] = f2bf_rne(v1.y);
  o[6] = f2bf_rne(v1.z); o[7] = f2bf_rne(v1.w);
  // chunk c -> k = c>>2, quad = c&3; lane = quad*16 + (row&15)
  *(u16x8*)(xb + FRAG_OFF(row >> 4, c >> 2, ((c & 3) * 16) + (row & 15))) = o;
  float s = v0.x * v0.x + v0.y * v0.y + v0.z * v0.z + v0.w * v0.w +
            v1.x * v1.x + v1.y * v1.y + v1.z * v1.z + v1.w * v1.w;
#pragma unroll
  for (int off = 1; off < 16; off <<= 1) s += __shfl_xor(s, off, 64);
  if (c == 0) {
    sq[row] = s;
    posw[row] = 0u;           // max(d2) accumulator
    negw[row] = 0x7F800000u;  // min(d2) accumulator = +inf
  }

  if (blockIdx.x == 0) {  // label histogram
    __shared__ unsigned h[8];
    if (t < 8) h[t] = 0u;
    __syncthreads();
    unsigned long long cA = 0ull, cB = 0ull;  // 4x16-bit packed counters each
#pragma unroll
    for (int it = 0; it < 32; ++it) {
      const int l = lab[t + it * 256] & 7;
      if (l < 4) cA += 1ull << (l * 16);
      else       cB += 1ull << ((l - 4) * 16);
    }
#pragma unroll
    for (int off = 1; off < 64; off <<= 1) {
      cA += __shfl_xor(cA, off, 64);
      cB += __shfl_xor(cB, off, 64);
    }
    if ((t & 63) == 0) {
#pragma unroll
      for (int q = 0; q < 4; ++q) {
        atomicAdd(&h[q],     (unsigned)((cA >> (q * 16)) & 0xFFFFu));
        atomicAdd(&h[4 + q], (unsigned)((cB >> (q * 16)) & 0xFFFFu));
      }
    }
    __syncthreads();
    if (t < 8) hist[t] = h[t];
    if (t == 0) { acc[0] = 0.f; acc[1] = 0.f; ticket[0] = 0u; }
  }
}

// ---------------- K2: symmetric GEMM + row/col mining (triangle, NO fences) ---
// Session ledger: k_mine insensitive to schedule tweaks (R3/R7/R8 all ~100us
// total); R1 proved the SYMMETRIC algorithm correct (absmax 0.0) but its 113us
// was ~38 mining + ~75 of per-block __threadfence (the fence costs ~70us/1000
// blocks: R4/R6 = 183us @ 2048). This round: R1 algorithm (0.52x tiles) on the
// R3 structure (depth-2 reg pipeline, separate k_tail -> only 32 fences),
// with amdgpu_waves_per_eu(4,4) pinning the allocator away from the R5/R6
// 64-reg+scratch trap. Col stats: per-js select/max in regs -> shfl across
// quads -> LDS keyed atomicMax/Min; block-level flush once at the end.
// Diag-parent blocks (bi>>1==bj) mine rows only: their 256x256 square covers
// both orientations row-wise; col-mine there would only double-count (max/min
// idempotent) and add the self-term (harmless: same-label -> pos, d2~0 loses).
__global__ __launch_bounds__(256)
__attribute__((amdgpu_waves_per_eu(4, 4)))
void k_mine(
    const unsigned short* __restrict__ xb, const float* __restrict__ sq,
    const int* __restrict__ lab, unsigned* __restrict__ posw, unsigned* __restrict__ negw) {
  __shared__ unsigned cposk[256], cnegk[256];

  const int t = threadIdx.x;
  const int w = t >> 6;
  const int lane = t & 63;
  const int col = lane & 15;   // MFMA m/n selector
  const int quad = lane >> 4;  // MFMA k-group / C row group

  // decode block -> (bi, bj): offset(bj) = bj*(bj+1)
  int bj, bi;
  {
    const int T = blockIdx.x;
    int b = (int)((sqrtf((float)(4 * T + 1)) - 1.0f) * 0.5f);
    while (b * (b + 1) > T) --b;
    while ((b + 1) * (b + 2) <= T) ++b;
    bj = b;
    bi = T - b * (b + 1);
  }
  const bool diag = ((bi >> 1) == bj);
  const int i0 = bi * 128 + w * 32;
  const int jbase = bj * 256;

  cposk[t] = 0u;
  cnegk[t] = 0xFFFFFFFFu;
  __syncthreads();

  // A fragments resident: 2 i-subtiles x 4 k-steps (coalesced loads)
  bf16x8 a[2][4];
#pragma unroll
  for (int is = 0; is < 2; ++is)
#pragma unroll
    for (int k = 0; k < 4; ++k)
      a[is][k] = *(const bf16x8*)(xb + FRAG_OFF((i0 >> 4) + is, k, lane));

  int labi[2][4];
  float sqi[2][4];
#pragma unroll
  for (int is = 0; is < 2; ++is)
#pragma unroll
    for (int r = 0; r < 4; ++r) {
      const int i = i0 + is * 16 + quad * 4 + r;
      labi[is][r] = lab[i];
      sqi[is][r] = sq[i];
    }

  float pos[2][4], neg[2][4];
#pragma unroll
  for (int is = 0; is < 2; ++is)
#pragma unroll
    for (int r = 0; r < 4; ++r) { pos[is][r] = -FLT_BIG; neg[is][r] = FLT_BIG; }

  const float* sqp = sq + jbase + col;
  const int* labp = lab + jbase + col;
  const unsigned short* gb = xb + FRAG_OFF(jbase >> 4, 0, lane);

  bf16x8 b0A, b1A, b2A, b3A, b0B, b1B, b2B, b3B;
  float sqjA, sqjB;
  int labjA, labjB;

#define LOADB(S, js_) do {                                        \
    const unsigned short* g = gb + (size_t)(js_) * 2048;          \
    b0##S = *(const bf16x8*)(g);                                  \
    b1##S = *(const bf16x8*)(g + 512);                            \
    b2##S = *(const bf16x8*)(g + 1024);                           \
    b3##S = *(const bf16x8*)(g + 1536);                           \
    sqj##S = sqp[(js_) * 16];                                     \
    labj##S = labp[(js_) * 16];                                   \
  } while (0)

#define COMPUTE(S, js_) do {                                                   \
    f32x4 acc0 = {0.f, 0.f, 0.f, 0.f}, acc1 = {0.f, 0.f, 0.f, 0.f};           \
    acc0 = __builtin_amdgcn_mfma_f32_16x16x32_bf16(a[0][0], b0##S, acc0, 0, 0, 0); \
    acc1 = __builtin_amdgcn_mfma_f32_16x16x32_bf16(a[1][0], b0##S, acc1, 0, 0, 0); \
    acc0 = __builtin_amdgcn_mfma_f32_16x16x32_bf16(a[0][1], b1##S, acc0, 0, 0, 0); \
    acc1 = __builtin_amdgcn_mfma_f32_16x16x32_bf16(a[1][1], b1##S, acc1, 0, 0, 0); \
    acc0 = __builtin_amdgcn_mfma_f32_16x16x32_bf16(a[0][2], b2##S, acc0, 0, 0, 0); \
    acc1 = __builtin_amdgcn_mfma_f32_16x16x32_bf16(a[1][2], b2##S, acc1, 0, 0, 0); \
    acc0 = __builtin_amdgcn_mfma_f32_16x16x32_bf16(a[0][3], b3##S, acc0, 0, 0, 0); \
    acc1 = __builtin_amdgcn_mfma_f32_16x16x32_bf16(a[1][3], b3##S, acc1, 0, 0, 0); \
    float cp = -FLT_BIG, cn = FLT_BIG;                                         \
    _Pragma("unroll")                                                          \
    for (int r = 0; r < 4; ++r) {                                              \
      const float m0 = fmaf(-2.f, acc0[r], sqj##S);                            \
      const float m1 = fmaf(-2.f, acc1[r], sqj##S);                            \
      const bool s0 = (labi[0][r] == labj##S);                                 \
      const bool s1 = (labi[1][r] == labj##S);                                 \
      pos[0][r] = fmaxf(pos[0][r], s0 ? m0 : -FLT_BIG);                        \
      neg[0][r] = fminf(neg[0][r], s0 ? FLT_BIG : m0);                         \
      pos[1][r] = fmaxf(pos[1][r], s1 ? m1 : -FLT_BIG);                        \
      neg[1][r] = fminf(neg[1][r], s1 ? FLT_BIG : m1);                         \
      if (!diag) {                                                             \
        const float mc0 = fmaf(-2.f, acc0[r], sqi[0][r]);                      \
        const float mc1 = fmaf(-2.f, acc1[r], sqi[1][r]);                      \
        cp = fmaxf(cp, s0 ? mc0 : -FLT_BIG);                                   \
        cn = fminf(cn, s0 ? FLT_BIG : mc0);                                    \
        cp = fmaxf(cp, s1 ? mc1 : -FLT_BIG);                                   \
        cn = fminf(cn, s1 ? FLT_BIG : mc1);                                    \
      }                                                                        \
    }                                                                          \
    if (!diag) {                                                               \
      cp = fmaxf(cp, __shfl_xor(cp, 16, 64));                                  \
      cp = fmaxf(cp, __shfl_xor(cp, 32, 64));                                  \
      cn = fminf(cn, __shfl_xor(cn, 16, 64));                                  \
      cn = fminf(cn, __shfl_xor(cn, 32, 64));                                  \
      if (quad == 0) {                                                         \
        atomicMax(&cposk[(js_) * 16 + col], fkey(cp));                         \
        atomicMin(&cnegk[(js_) * 16 + col], fkey(cn));                         \
      }                                                                        \
    }                                                                          \
  } while (0)

  // depth-2 pipeline (R3-proven): A holds js, B holds js+1.
  LOADB(A, 0);
#pragma unroll 1
  for (int js = 0; js < 14; js += 2) {
    LOADB(B, js + 1);
    COMPUTE(A, js);
    LOADB(A, js + 2);
    COMPUTE(B, js + 1);
  }
  LOADB(B, 15);
  COMPUTE(A, 14);
  COMPUTE(B, 15);

#undef LOADB
#undef COMPUTE

  // row flush: reduce the 16 cols sharing each i-row, add sq_i, atomics
#pragma unroll
  for (int is = 0; is < 2; ++is)
#pragma unroll
    for (int r = 0; r < 4; ++r) {
      float p = pos[is][r], n = neg[is][r];
#pragma unroll
      for (int off = 1; off < 16; off <<= 1) {
        p = fmaxf(p, __shfl_xor(p, off, 64));
        n = fminf(n, __shfl_xor(n, off, 64));
      }
      if (col == 0) {
        const int i = i0 + is * 16 + quad * 4 + r;
        atomicMax(posw + i, __float_as_uint(fmaxf(sqi[is][r] + p, 0.f)));
        atomicMin(negw + i, __float_as_uint(fmaxf(sqi[is][r] + n, 0.f)));
      }
    }

  // col flush: one col per thread (off-diag blocks only; block-uniform branch)
  if (!diag) {
    __syncthreads();
    const int j = jbase + t;
    const float cpv = fkey_inv(cposk[t]);
    const float cnv = fkey_inv(cnegk[t]);
    const float sqj = sq[j];
    atomicMax(posw + j, __float_as_uint(fmaxf(sqj + cpv, 0.f)));
    atomicMin(negw + j, __float_as_uint(fmaxf(sqj + cnv, 0.f)));
  }
}

// ---------------- K3: per-row loss + global reduce + finalize (ticketed) -----
__global__ void k_tail(const unsigned* __restrict__ posw, const unsigned* __restrict__ negw,
                       const int* __restrict__ lab, const unsigned* __restrict__ hist,
                       float* __restrict__ acc, unsigned* __restrict__ ticket,
                       float* __restrict__ out) {
  __shared__ float ls[4], cs[4];
  const int t = threadIdx.x;
  const int i = blockIdx.x * 256 + t;
  const float pd2 = __uint_as_float(posw[i]);
  const float nd2 = __uint_as_float(negw[i]);
  const unsigned cnt = hist[lab[i] & 7];
  const bool valid = (cnt >= 2u) && (cnt < (unsigned)N);
  float loss = 0.f, c = 0.f;
  if (valid) {
    loss = fmaxf(sqrtf(pd2) - sqrtf(fminf(nd2, FLT_BIG)) + MARGIN, 0.f);
    c = 1.f;
  }
#pragma unroll
  for (int off = 1; off < 64; off <<= 1) {
    loss += __shfl_xor(loss, off, 64);
    c += __shfl_xor(c, off, 64);
  }
  const int wv = t >> 6;
  if ((t & 63) == 0) { ls[wv] = loss; cs[wv] = c; }
  __syncthreads();
  if (t == 0) {
    atomicAdd(acc + 0, ls[0] + ls[1] + ls[2] + ls[3]);
    atomicAdd(acc + 1, cs[0] + cs[1] + cs[2] + cs[3]);
    __threadfence();
    const unsigned tk = atomicAdd(ticket, 1u);
    if (tk == 31u) {  // last block: partials fenced-in; read via atomics (coherent)
      const float lsum = atomicAdd(acc + 0, 0.f);
      const float csum = atomicAdd(acc + 1, 0.f);
      out[0] = lsum / fmaxf(csum, 1.f);
    }
  }
}

extern "C" void kernel_launch(void* const* d_in, const int* in_sizes, int n_in,
                              void* d_out, int out_size, void* d_ws, size_t ws_size,
                              hipStream_t stream) {
  const float* x = (const float*)d_in[0];
  const int* lab = (const int*)d_in[1];
  char* ws = (char*)d_ws;
  unsigned short* xb = (unsigned short*)ws;                 // 2 MB bf16 fragment-swizzled
  float* sq = (float*)(ws + (size_t)N * D * 2);             // 32 KB
  unsigned* posw = (unsigned*)((char*)sq + (size_t)N * 4);  // 32 KB
  unsigned* negw = posw + N;                                // 32 KB
  unsigned* hist = negw + N;                                // 32 B
  unsigned* ticket = hist + 8;                              // 4 B
  float* acc = (float*)(ticket + 1);                        // 8 B
  float* out = (float*)d_out;

  hipLaunchKernelGGL(k_prep, dim3(512), dim3(256), 0, stream, x, lab, xb, sq,
                     posw, negw, hist, acc, ticket);
  hipLaunchKernelGGL(k_mine, dim3(NBLK), dim3(256), 0, stream, xb, sq, lab, posw, negw);
  hipLaunchKernelGGL(k_tail, dim3(32), dim3(256), 0, stream, posw, negw, lab, hist,
                     acc, ticket, out);
}